// Round 1
// baseline (179.361 us; speedup 1.0000x reference)
//
#include <hip/hip_runtime.h>
#include <math.h>

#define N_DIM 1024
#define G_DIM 4096
#define B_DIM 2048
#define K2DIM 2048  // 2*N (real|imag concatenated K)

typedef __attribute__((ext_vector_type(8))) short bf16x8;
typedef __attribute__((ext_vector_type(4))) float f32x4;
typedef unsigned short ushort_t;

// ---------- ws layout (bytes) ----------
#define WS_BRT   0u                      // bf16 [G][2048]  16 MB
#define WS_BIT   (16u << 20)             // bf16 [G][2048]  16 MB
#define WS_HBF   (32u << 20)             // bf16 [B][2048]   8 MB
#define WS_ROWMAX (40u << 20)            // u32 [B]
#define WS_CCNT  (WS_ROWMAX + 8192u)     // int [B]
#define WS_CG    (WS_CCNT + 8192u)       // int [B][64]
#define WS_WG    (WS_CG + 2048u*64u*4u)  // int [B]
#define WS_WXR   (WS_WG + 8192u)         // f32 [B]
#define WS_WXI   (WS_WXR + 8192u)        // f32 [B]

__device__ __forceinline__ unsigned short f2bf(float f) {
  unsigned u = __float_as_uint(f);
  unsigned r = u + 0x7fffu + ((u >> 16) & 1u);
  return (unsigned short)(r >> 16);
}

__device__ __forceinline__ void gload_lds16(const void* gsrc, void* ldst) {
  __builtin_amdgcn_global_load_lds(
      (const __attribute__((address_space(1))) void*)gsrc,
      (__attribute__((address_space(3))) void*)ldst, 16, 0, 0);
}

// ---------- K1: PSI generation (transposed outputs) ----------
__global__ void k_psi(const float* __restrict__ theta, const float* __restrict__ alpha,
                      float* __restrict__ prT, float* __restrict__ piT,
                      ushort_t* __restrict__ brT, ushort_t* __restrict__ biT) {
  __shared__ float sp[32][33], si[32][33];
  const int tx = threadIdx.x, ty = threadIdx.y;
  const int g0 = blockIdx.x * 32, n0 = blockIdx.y * 32;
  for (int rr = ty; rr < 32; rr += 8) {
    const size_t idx = (size_t)(n0 + rr) * G_DIM + g0 + tx;
    float a = tanhf(alpha[idx]) * 0.03125f;  // 1/sqrt(1024)
    float s, c;
    sincosf(theta[idx], &s, &c);
    sp[rr][tx] = a * c;
    si[rr][tx] = a * s;
  }
  __syncthreads();
  for (int rr = ty; rr < 32; rr += 8) {
    const int g = g0 + rr, n = n0 + tx;
    const float pr = sp[tx][rr], pi = si[tx][rr];
    prT[(size_t)g * N_DIM + n] = pr;
    piT[(size_t)g * N_DIM + n] = pi;
    brT[(size_t)g * K2DIM + n] = f2bf(pr);
    brT[(size_t)g * K2DIM + N_DIM + n] = f2bf(-pi);
    biT[(size_t)g * K2DIM + n] = f2bf(pi);
    biT[(size_t)g * K2DIM + N_DIM + n] = f2bf(pr);
  }
}

// ---------- K1b: H -> bf16, layout [B][2048] (Hr | Hi) ----------
__global__ void k_hconv(const float* __restrict__ H, ushort_t* __restrict__ hbf) {
  const int j4 = (blockIdx.x * blockDim.x + threadIdx.x) * 4;
  const int b = j4 >> 11, k = j4 & 2047, c = k >> 10, n = k & 1023;
  const float4 v = *reinterpret_cast<const float4*>(
      H + (size_t)c * (B_DIM * N_DIM) + (size_t)b * N_DIM + n);
  ushort4 u;
  u.x = f2bf(v.x); u.y = f2bf(v.y); u.z = f2bf(v.z); u.w = f2bf(v.w);
  *reinterpret_cast<ushort4*>(hbf + j4) = u;
}

// ---------- K2: bf16 MFMA GEMM -> |x|^2 + per-row max ----------
__global__ __launch_bounds__(256, 2) void k_gemm(
    const ushort_t* __restrict__ hbf, const ushort_t* __restrict__ brT,
    const ushort_t* __restrict__ biT, float* __restrict__ xabs,
    unsigned* __restrict__ rowmax) {
  __shared__ ushort_t sA[4096], sBr[4096], sBi[4096];  // 128x32 tiles
  __shared__ unsigned tilemax[128];
  const int tid = threadIdx.x;
  const int l = tid & 63, w = tid >> 6;
  const int wm = w >> 1, wn = w & 1;
  const int g0 = blockIdx.x * 128, b0 = blockIdx.y * 128;

  f32x4 accr[4][4], acci[4][4];
#pragma unroll
  for (int i = 0; i < 4; ++i)
#pragma unroll
    for (int j = 0; j < 4; ++j) {
      accr[i][j] = (f32x4){0.f, 0.f, 0.f, 0.f};
      acci[i][j] = (f32x4){0.f, 0.f, 0.f, 0.f};
    }

  const int srow = l >> 2;          // row-in-chunk
  const int scol = (l & 3) * 8;     // elem col offset
  const int ar = l & 15, ak = (l >> 4) * 8;

  for (int kk = 0; kk < K2DIM; kk += 32) {
    __syncthreads();
#pragma unroll
    for (int j = 0; j < 6; ++j) {
      const int c = w * 6 + j;
      const int cc = c & 7;
      const int row = cc * 16 + srow;
      if (c < 8) {
        gload_lds16(hbf + ((size_t)(b0 + row) * K2DIM + kk + scol), (void*)(sA + cc * 512));
      } else if (c < 16) {
        gload_lds16(brT + ((size_t)(g0 + row) * K2DIM + kk + scol), (void*)(sBr + cc * 512));
      } else {
        gload_lds16(biT + ((size_t)(g0 + row) * K2DIM + kk + scol), (void*)(sBi + cc * 512));
      }
    }
    __syncthreads();

    bf16x8 af[4], brf[4], bif[4];
#pragma unroll
    for (int mi = 0; mi < 4; ++mi)
      af[mi] = *(const bf16x8*)&sA[(wm * 64 + mi * 16 + ar) * 32 + ak];
#pragma unroll
    for (int ni = 0; ni < 4; ++ni) {
      brf[ni] = *(const bf16x8*)&sBr[(wn * 64 + ni * 16 + ar) * 32 + ak];
      bif[ni] = *(const bf16x8*)&sBi[(wn * 64 + ni * 16 + ar) * 32 + ak];
    }
#pragma unroll
    for (int mi = 0; mi < 4; ++mi)
#pragma unroll
      for (int ni = 0; ni < 4; ++ni) {
        accr[mi][ni] = __builtin_amdgcn_mfma_f32_16x16x32_bf16(af[mi], brf[ni], accr[mi][ni], 0, 0, 0);
        acci[mi][ni] = __builtin_amdgcn_mfma_f32_16x16x32_bf16(af[mi], bif[ni], acci[mi][ni], 0, 0, 0);
      }
  }

  __syncthreads();
  if (tid < 128) tilemax[tid] = 0u;
  __syncthreads();

#pragma unroll
  for (int mi = 0; mi < 4; ++mi)
#pragma unroll
    for (int ni = 0; ni < 4; ++ni) {
      const int gcol = g0 + wn * 64 + ni * 16 + (l & 15);
      const int mbase = wm * 64 + mi * 16 + (l >> 4) * 4;
      const f32x4 r = accr[mi][ni], q = acci[mi][ni];
#pragma unroll
      for (int i = 0; i < 4; ++i) {
        const float xab = r[i] * r[i] + q[i] * q[i];
        xabs[(size_t)(b0 + mbase + i) * G_DIM + gcol] = xab;
        atomicMax(&tilemax[mbase + i], __float_as_uint(xab));
      }
    }
  __syncthreads();
  if (tid < 128) atomicMax(&rowmax[b0 + tid], tilemax[tid]);
}

// ---------- K2b: candidate scan ----------
__global__ void k_scan(const float* __restrict__ xabs, const unsigned* __restrict__ rowmax,
                       int* __restrict__ ccnt, int* __restrict__ cg) {
  const size_t e0 = ((size_t)blockIdx.x * 256 + threadIdx.x) * 4;
  const int b = (int)(e0 >> 12);
  const float thr = __uint_as_float(rowmax[b]) - 0.25f;
  const float4 v = *reinterpret_cast<const float4*>(xabs + e0);
  const int gb = (int)(e0 & 4095);
  if (v.x >= thr) { int p = atomicAdd(&ccnt[b], 1); if (p < 64) cg[b * 64 + p] = gb; }
  if (v.y >= thr) { int p = atomicAdd(&ccnt[b], 1); if (p < 64) cg[b * 64 + p] = gb + 1; }
  if (v.z >= thr) { int p = atomicAdd(&ccnt[b], 1); if (p < 64) cg[b * 64 + p] = gb + 2; }
  if (v.w >= thr) { int p = atomicAdd(&ccnt[b], 1); if (p < 64) cg[b * 64 + p] = gb + 3; }
}

// ---------- K3: fp64 refinement of candidates -> winner ----------
__global__ void k_refine(const float* __restrict__ H, const float* __restrict__ prT,
                         const float* __restrict__ piT, const int* __restrict__ ccnt,
                         const int* __restrict__ cg, int* __restrict__ wg,
                         float* __restrict__ wxr, float* __restrict__ wxi) {
  __shared__ double red[8];
  const int b = blockIdx.x, tid = threadIdx.x;
  const int l = tid & 63, w = tid >> 6;
  int cnt = ccnt[b];
  if (cnt > 64) cnt = 64;
  double best = -1.0, bxr = 0.0, bxi = 0.0;
  int bg = 0;
  for (int ci = 0; ci < cnt; ++ci) {
    const int g = cg[b * 64 + ci];
    double xr = 0.0, xi = 0.0;
    for (int n = tid; n < N_DIM; n += 256) {
      const double hr = H[(size_t)b * N_DIM + n];
      const double hi = H[(size_t)B_DIM * N_DIM + (size_t)b * N_DIM + n];
      const double pr = prT[(size_t)g * N_DIM + n];
      const double pi = piT[(size_t)g * N_DIM + n];
      xr += hr * pr - hi * pi;
      xi += hr * pi + hi * pr;
    }
    for (int off = 32; off; off >>= 1) {
      xr += __shfl_down(xr, off);
      xi += __shfl_down(xi, off);
    }
    if (l == 0) { red[w * 2] = xr; red[w * 2 + 1] = xi; }
    __syncthreads();
    if (tid == 0) {
      const double sxr = red[0] + red[2] + red[4] + red[6];
      const double sxi = red[1] + red[3] + red[5] + red[7];
      const double xab = sxr * sxr + sxi * sxi;
      if (xab > best || (xab == best && g < bg)) { best = xab; bg = g; bxr = sxr; bxi = sxi; }
    }
    __syncthreads();
  }
  if (tid == 0) { wg[b] = bg; wxr[b] = (float)bxr; wxi[b] = (float)bxi; }
}

// ---------- K4: y = winner x conj(PSI column) ----------
__global__ void k_y(const float* __restrict__ prT, const float* __restrict__ piT,
                    const int* __restrict__ wg, const float* __restrict__ wxr,
                    const float* __restrict__ wxi, float* __restrict__ out) {
  const int b = blockIdx.x, tid = threadIdx.x;
  const int g = wg[b];
  const float xr = wxr[b], xi = wxi[b];
  float* yr = out + (size_t)2 * B_DIM * G_DIM + (size_t)b * N_DIM;
  float* yi = yr + (size_t)B_DIM * N_DIM;
  for (int n = tid; n < N_DIM; n += 256) {
    const float pr = prT[(size_t)g * N_DIM + n], pi = piT[(size_t)g * N_DIM + n];
    yr[n] = xr * pr + xi * pi;
    yi[n] = xi * pr - xr * pi;
  }
}

// ---------- K5: scatter winner values into zeroed x ----------
__global__ void k_scatter(const int* __restrict__ wg, const float* __restrict__ wxr,
                          const float* __restrict__ wxi, float* __restrict__ out) {
  const int b = blockIdx.x * 256 + threadIdx.x;
  if (b < B_DIM) {
    const int g = wg[b];
    out[(size_t)b * G_DIM + g] = wxr[b];
    out[(size_t)B_DIM * G_DIM + (size_t)b * G_DIM + g] = wxi[b];
  }
}

extern "C" void kernel_launch(void* const* d_in, const int* in_sizes, int n_in,
                              void* d_out, int out_size, void* d_ws, size_t ws_size,
                              hipStream_t stream) {
  const float* H = (const float*)d_in[0];
  const float* theta = (const float*)d_in[1];
  const float* alpha = (const float*)d_in[2];
  float* out = (float*)d_out;
  char* ws = (char*)d_ws;

  ushort_t* brT = (ushort_t*)(ws + WS_BRT);
  ushort_t* biT = (ushort_t*)(ws + WS_BIT);
  ushort_t* hbf = (ushort_t*)(ws + WS_HBF);
  unsigned* rowmax = (unsigned*)(ws + WS_ROWMAX);
  int* ccnt = (int*)(ws + WS_CCNT);
  int* cg = (int*)(ws + WS_CG);
  int* wg = (int*)(ws + WS_WG);
  float* wxr = (float*)(ws + WS_WXR);
  float* wxi = (float*)(ws + WS_WXI);

  // d_out x-region doubles as scratch until the final memset+scatter:
  float* prT = out;                 // [G][N] f32, 16 MB
  float* piT = out + 4194304;       // 16 MB
  float* xabs = out + 8388608;      // [B][G] f32, 32 MB

  hipMemsetAsync(ws + WS_ROWMAX, 0, 16384, stream);  // rowmax + ccnt

  k_psi<<<dim3(G_DIM / 32, N_DIM / 32), dim3(32, 8), 0, stream>>>(theta, alpha, prT, piT, brT, biT);
  k_hconv<<<4096, 256, 0, stream>>>(H, hbf);
  k_gemm<<<dim3(G_DIM / 128, B_DIM / 128), 256, 0, stream>>>(hbf, brT, biT, xabs, rowmax);
  k_scan<<<8192, 256, 0, stream>>>(xabs, rowmax, ccnt, cg);
  k_refine<<<B_DIM, 256, 0, stream>>>(H, prT, piT, ccnt, cg, wg, wxr, wxi);
  k_y<<<B_DIM, 256, 0, stream>>>(prT, piT, wg, wxr, wxi, out);
  hipMemsetAsync(out, 0, (size_t)2 * B_DIM * G_DIM * 4, stream);  // zero x-region
  k_scatter<<<8, 256, 0, stream>>>(wg, wxr, wxi, out);
}

// Round 2
// 158.438 us; speedup vs baseline: 1.1321x; 1.1321x over previous
//
#include <hip/hip_runtime.h>
#include <math.h>

#define N_DIM 1024
#define G_DIM 4096
#define B_DIM 2048
#define K2DIM 2048  // 2*N (real|imag concatenated K)

typedef __attribute__((ext_vector_type(8))) short bf16x8;
typedef __attribute__((ext_vector_type(4))) float f32x4;
typedef unsigned short ushort_t;

// ---------- ws layout (bytes) ----------
#define WS_BRT   0u                      // bf16 [G][2048]  16 MB
#define WS_BIT   (16u << 20)             // bf16 [G][2048]  16 MB
#define WS_HBF   (32u << 20)             // bf16 [B][2048]   8 MB
#define WS_ROWMAX (40u << 20)            // u32 [B]
#define WS_CCNT  (WS_ROWMAX + 8192u)     // int [B]
#define WS_CG    (WS_CCNT + 8192u)       // int [B][64]
#define WS_WG    (WS_CG + 2048u*64u*4u)  // int [B]
#define WS_WXR   (WS_WG + 8192u)         // f32 [B]
#define WS_WXI   (WS_WXR + 8192u)        // f32 [B]

__device__ __forceinline__ unsigned short f2bf(float f) {
  unsigned u = __float_as_uint(f);
  unsigned r = u + 0x7fffu + ((u >> 16) & 1u);
  return (unsigned short)(r >> 16);
}

__device__ __forceinline__ void gload_lds16(const void* gsrc, void* ldst) {
  __builtin_amdgcn_global_load_lds(
      (const __attribute__((address_space(1))) void*)gsrc,
      (__attribute__((address_space(3))) void*)ldst, 16, 0, 0);
}

// ---------- K1: PSI generation (transposed outputs) ----------
__global__ void k_psi(const float* __restrict__ theta, const float* __restrict__ alpha,
                      float* __restrict__ prT, float* __restrict__ piT,
                      ushort_t* __restrict__ brT, ushort_t* __restrict__ biT) {
  __shared__ float sp[32][33], si[32][33];
  const int tx = threadIdx.x, ty = threadIdx.y;
  const int g0 = blockIdx.x * 32, n0 = blockIdx.y * 32;
  for (int rr = ty; rr < 32; rr += 8) {
    const size_t idx = (size_t)(n0 + rr) * G_DIM + g0 + tx;
    float a = tanhf(alpha[idx]) * 0.03125f;  // 1/sqrt(1024)
    float s, c;
    sincosf(theta[idx], &s, &c);
    sp[rr][tx] = a * c;
    si[rr][tx] = a * s;
  }
  __syncthreads();
  for (int rr = ty; rr < 32; rr += 8) {
    const int g = g0 + rr, n = n0 + tx;
    const float pr = sp[tx][rr], pi = si[tx][rr];
    prT[(size_t)g * N_DIM + n] = pr;
    piT[(size_t)g * N_DIM + n] = pi;
    brT[(size_t)g * K2DIM + n] = f2bf(pr);
    brT[(size_t)g * K2DIM + N_DIM + n] = f2bf(-pi);
    biT[(size_t)g * K2DIM + n] = f2bf(pi);
    biT[(size_t)g * K2DIM + N_DIM + n] = f2bf(pr);
  }
}

// ---------- K1b: H -> bf16, layout [B][2048] (Hr | Hi) ----------
__global__ void k_hconv(const float* __restrict__ H, ushort_t* __restrict__ hbf) {
  const int j4 = (blockIdx.x * blockDim.x + threadIdx.x) * 4;
  const int b = j4 >> 11, k = j4 & 2047, c = k >> 10, n = k & 1023;
  const float4 v = *reinterpret_cast<const float4*>(
      H + (size_t)c * (B_DIM * N_DIM) + (size_t)b * N_DIM + n);
  ushort4 u;
  u.x = f2bf(v.x); u.y = f2bf(v.y); u.z = f2bf(v.z); u.w = f2bf(v.w);
  *reinterpret_cast<ushort4*>(hbf + j4) = u;
}

// ---------- K2: 8-phase dual-acc bf16 MFMA GEMM -> |x|^2 + per-row max ----------
// BM=256 (batch rows), BN=128 (G cols), BK=64. 8 waves (2M x 4N).
// LDS: dbuf x (A 32K + Br 16K + Bi 16K) = 128 KB, XOR slot-swizzled (T2).
__global__ __launch_bounds__(512, 2) void k_gemm(
    const ushort_t* __restrict__ hbf, const ushort_t* __restrict__ brT,
    const ushort_t* __restrict__ biT, float* __restrict__ xabs,
    unsigned* __restrict__ rowmax) {
  __shared__ ushort_t smem[65536];     // 128 KB
  __shared__ unsigned tilemax[256];
  const int tid = threadIdx.x;
  const int l = tid & 63, w = tid >> 6;
  const int wm = w >> 2, wn = w & 3;
  // bijective XCD swizzle: XCD x owns one full A row-panel (nwg=256, 8 XCDs)
  const int bid = blockIdx.x;
  const int wgid = (bid & 7) * 32 + (bid >> 3);
  const int g0 = (wgid & 31) * 128, b0 = (wgid >> 5) * 256;

  // fragment read offsets (ushort elems); rows are 128B so bank = slot only.
  // swizzle: slot ^= (row&7); row&7 == l&7 for all frag rows (bases mult of 16)
  int colK[2];
#pragma unroll
  for (int ks = 0; ks < 2; ++ks)
    colK[ks] = (ks * 32 + (l >> 4) * 8) ^ ((l & 7) << 3);
  int rowA[8], rowB[2];
#pragma unroll
  for (int mi = 0; mi < 8; ++mi) rowA[mi] = (wm * 128 + mi * 16 + (l & 15)) * 64;
#pragma unroll
  for (int ni = 0; ni < 2; ++ni) rowB[ni] = (wn * 32 + ni * 16 + (l & 15)) * 64;

  // staging: linear LDS dest (gload_lds), pre-swizzled global source (rule #21)
  const ushort_t* sApt[4];
  const ushort_t* sBrpt[2];
  const ushort_t* sBipt[2];
  int dA[4], dB[2];
#pragma unroll
  for (int i = 0; i < 4; ++i) {
    const int sl = i * 512 + tid, r = sl >> 3, c = (sl & 7) ^ (r & 7);
    sApt[i] = hbf + (size_t)(b0 + r) * K2DIM + c * 8;
    dA[i] = (i * 512 + (tid & ~63)) * 8;
  }
#pragma unroll
  for (int i = 0; i < 2; ++i) {
    const int sl = i * 512 + tid, r = sl >> 3, c = (sl & 7) ^ (r & 7);
    sBrpt[i] = brT + (size_t)(g0 + r) * K2DIM + c * 8;
    sBipt[i] = biT + (size_t)(g0 + r) * K2DIM + c * 8;
    dB[i] = (i * 512 + (tid & ~63)) * 8;
  }

  f32x4 accr[8][2], acci[8][2];
#pragma unroll
  for (int mi = 0; mi < 8; ++mi)
#pragma unroll
    for (int ni = 0; ni < 2; ++ni) {
      accr[mi][ni] = (f32x4){0.f, 0.f, 0.f, 0.f};
      acci[mi][ni] = (f32x4){0.f, 0.f, 0.f, 0.f};
    }

  // prologue: stage tile 0 into buf 0
#pragma unroll
  for (int i = 0; i < 4; ++i) gload_lds16(sApt[i], (void*)(smem + dA[i]));
#pragma unroll
  for (int i = 0; i < 2; ++i) {
    gload_lds16(sBrpt[i], (void*)(smem + 16384 + dB[i]));
    gload_lds16(sBipt[i], (void*)(smem + 24576 + dB[i]));
  }
  asm volatile("s_waitcnt vmcnt(0)" ::: "memory");
  __syncthreads();

  bf16x8 a[4][2], br[2][2], bi[2][2];

  for (int t = 0; t < 32; ++t) {
    const int cb = (t & 1) * 32768;
    const int nb = ((t + 1) & 1) * 32768;
    const int kp = (t + 1) * 64;
    const bool pf = (t < 31);
    const ushort_t* bufA = smem + cb;
    const ushort_t* bufBr = smem + cb + 16384;
    const ushort_t* bufBi = smem + cb + 24576;

    // ---- P1: read A-half0 + Br; issue A prefetch; accr half0
#pragma unroll
    for (int mi = 0; mi < 4; ++mi)
#pragma unroll
      for (int ks = 0; ks < 2; ++ks)
        a[mi][ks] = *(const bf16x8*)&bufA[rowA[mi] + colK[ks]];
#pragma unroll
    for (int ni = 0; ni < 2; ++ni)
#pragma unroll
      for (int ks = 0; ks < 2; ++ks)
        br[ni][ks] = *(const bf16x8*)&bufBr[rowB[ni] + colK[ks]];
    if (pf) {
#pragma unroll
      for (int i = 0; i < 4; ++i)
        gload_lds16(sApt[i] + kp, (void*)(smem + nb + dA[i]));
    }
    __builtin_amdgcn_s_barrier();
    asm volatile("s_waitcnt lgkmcnt(0)" ::: "memory");
    __builtin_amdgcn_sched_barrier(0);
    __builtin_amdgcn_s_setprio(1);
#pragma unroll
    for (int mi = 0; mi < 4; ++mi)
#pragma unroll
      for (int ni = 0; ni < 2; ++ni)
#pragma unroll
        for (int ks = 0; ks < 2; ++ks)
          accr[mi][ni] = __builtin_amdgcn_mfma_f32_16x16x32_bf16(a[mi][ks], br[ni][ks], accr[mi][ni], 0, 0, 0);
    __builtin_amdgcn_s_setprio(0);
    __builtin_amdgcn_s_barrier();

    // ---- P2: read Bi; issue B prefetch; acci half0
#pragma unroll
    for (int ni = 0; ni < 2; ++ni)
#pragma unroll
      for (int ks = 0; ks < 2; ++ks)
        bi[ni][ks] = *(const bf16x8*)&bufBi[rowB[ni] + colK[ks]];
    if (pf) {
#pragma unroll
      for (int i = 0; i < 2; ++i) {
        gload_lds16(sBrpt[i] + kp, (void*)(smem + nb + 16384 + dB[i]));
        gload_lds16(sBipt[i] + kp, (void*)(smem + nb + 24576 + dB[i]));
      }
    }
    __builtin_amdgcn_s_barrier();
    asm volatile("s_waitcnt lgkmcnt(0)" ::: "memory");
    __builtin_amdgcn_sched_barrier(0);
    __builtin_amdgcn_s_setprio(1);
#pragma unroll
    for (int mi = 0; mi < 4; ++mi)
#pragma unroll
      for (int ni = 0; ni < 2; ++ni)
#pragma unroll
        for (int ks = 0; ks < 2; ++ks)
          acci[mi][ni] = __builtin_amdgcn_mfma_f32_16x16x32_bf16(a[mi][ks], bi[ni][ks], acci[mi][ni], 0, 0, 0);
    __builtin_amdgcn_s_setprio(0);
    __builtin_amdgcn_s_barrier();

    // ---- P3: read A-half1; accr half1
#pragma unroll
    for (int mi = 0; mi < 4; ++mi)
#pragma unroll
      for (int ks = 0; ks < 2; ++ks)
        a[mi][ks] = *(const bf16x8*)&bufA[rowA[mi + 4] + colK[ks]];
    __builtin_amdgcn_s_barrier();
    asm volatile("s_waitcnt lgkmcnt(0)" ::: "memory");
    __builtin_amdgcn_sched_barrier(0);
    __builtin_amdgcn_s_setprio(1);
#pragma unroll
    for (int mi = 0; mi < 4; ++mi)
#pragma unroll
      for (int ni = 0; ni < 2; ++ni)
#pragma unroll
        for (int ks = 0; ks < 2; ++ks)
          accr[mi + 4][ni] = __builtin_amdgcn_mfma_f32_16x16x32_bf16(a[mi][ks], br[ni][ks], accr[mi + 4][ni], 0, 0, 0);
    __builtin_amdgcn_s_setprio(0);
    __builtin_amdgcn_s_barrier();

    // ---- P4: acci half1 (pure register); then per-K-tile drain
    __builtin_amdgcn_s_setprio(1);
#pragma unroll
    for (int mi = 0; mi < 4; ++mi)
#pragma unroll
      for (int ni = 0; ni < 2; ++ni)
#pragma unroll
        for (int ks = 0; ks < 2; ++ks)
          acci[mi + 4][ni] = __builtin_amdgcn_mfma_f32_16x16x32_bf16(a[mi][ks], bi[ni][ks], acci[mi + 4][ni], 0, 0, 0);
    __builtin_amdgcn_s_setprio(0);
    asm volatile("s_waitcnt vmcnt(0)" ::: "memory");
    __syncthreads();
  }

  // epilogue: |x|^2 + per-row max
  if (tid < 256) tilemax[tid] = 0u;
  __syncthreads();
#pragma unroll
  for (int mi = 0; mi < 8; ++mi)
#pragma unroll
    for (int ni = 0; ni < 2; ++ni) {
      const int gcol = g0 + wn * 32 + ni * 16 + (l & 15);
      const int mb = wm * 128 + mi * 16 + (l >> 4) * 4;
      const f32x4 r = accr[mi][ni], q = acci[mi][ni];
#pragma unroll
      for (int i = 0; i < 4; ++i) {
        const float xab = r[i] * r[i] + q[i] * q[i];
        xabs[(size_t)(b0 + mb + i) * G_DIM + gcol] = xab;
        atomicMax(&tilemax[mb + i], __float_as_uint(xab));
      }
    }
  __syncthreads();
  if (tid < 256) atomicMax(&rowmax[b0 + tid], tilemax[tid]);
}

// ---------- K2b: candidate scan ----------
__global__ void k_scan(const float* __restrict__ xabs, const unsigned* __restrict__ rowmax,
                       int* __restrict__ ccnt, int* __restrict__ cg) {
  const size_t e0 = ((size_t)blockIdx.x * 256 + threadIdx.x) * 4;
  const int b = (int)(e0 >> 12);
  const float thr = __uint_as_float(rowmax[b]) - 0.25f;
  const float4 v = *reinterpret_cast<const float4*>(xabs + e0);
  const int gb = (int)(e0 & 4095);
  if (v.x >= thr) { int p = atomicAdd(&ccnt[b], 1); if (p < 64) cg[b * 64 + p] = gb; }
  if (v.y >= thr) { int p = atomicAdd(&ccnt[b], 1); if (p < 64) cg[b * 64 + p] = gb + 1; }
  if (v.z >= thr) { int p = atomicAdd(&ccnt[b], 1); if (p < 64) cg[b * 64 + p] = gb + 2; }
  if (v.w >= thr) { int p = atomicAdd(&ccnt[b], 1); if (p < 64) cg[b * 64 + p] = gb + 3; }
}

// ---------- K3: fp64 refinement of candidates -> winner ----------
__global__ void k_refine(const float* __restrict__ H, const float* __restrict__ prT,
                         const float* __restrict__ piT, const int* __restrict__ ccnt,
                         const int* __restrict__ cg, int* __restrict__ wg,
                         float* __restrict__ wxr, float* __restrict__ wxi) {
  __shared__ double red[8];
  const int b = blockIdx.x, tid = threadIdx.x;
  const int l = tid & 63, w = tid >> 6;
  int cnt = ccnt[b];
  if (cnt > 64) cnt = 64;
  double best = -1.0, bxr = 0.0, bxi = 0.0;
  int bg = 0;
  for (int ci = 0; ci < cnt; ++ci) {
    const int g = cg[b * 64 + ci];
    double xr = 0.0, xi = 0.0;
    for (int n = tid; n < N_DIM; n += 256) {
      const double hr = H[(size_t)b * N_DIM + n];
      const double hi = H[(size_t)B_DIM * N_DIM + (size_t)b * N_DIM + n];
      const double pr = prT[(size_t)g * N_DIM + n];
      const double pi = piT[(size_t)g * N_DIM + n];
      xr += hr * pr - hi * pi;
      xi += hr * pi + hi * pr;
    }
    for (int off = 32; off; off >>= 1) {
      xr += __shfl_down(xr, off);
      xi += __shfl_down(xi, off);
    }
    if (l == 0) { red[w * 2] = xr; red[w * 2 + 1] = xi; }
    __syncthreads();
    if (tid == 0) {
      const double sxr = red[0] + red[2] + red[4] + red[6];
      const double sxi = red[1] + red[3] + red[5] + red[7];
      const double xab = sxr * sxr + sxi * sxi;
      if (xab > best || (xab == best && g < bg)) { best = xab; bg = g; bxr = sxr; bxi = sxi; }
    }
    __syncthreads();
  }
  if (tid == 0) { wg[b] = bg; wxr[b] = (float)bxr; wxi[b] = (float)bxi; }
}

// ---------- K4: y = winner x conj(PSI column) ----------
__global__ void k_y(const float* __restrict__ prT, const float* __restrict__ piT,
                    const int* __restrict__ wg, const float* __restrict__ wxr,
                    const float* __restrict__ wxi, float* __restrict__ out) {
  const int b = blockIdx.x, tid = threadIdx.x;
  const int g = wg[b];
  const float xr = wxr[b], xi = wxi[b];
  float* yr = out + (size_t)2 * B_DIM * G_DIM + (size_t)b * N_DIM;
  float* yi = yr + (size_t)B_DIM * N_DIM;
  for (int n = tid; n < N_DIM; n += 256) {
    const float pr = prT[(size_t)g * N_DIM + n], pi = piT[(size_t)g * N_DIM + n];
    yr[n] = xr * pr + xi * pi;
    yi[n] = xi * pr - xr * pi;
  }
}

// ---------- K5: scatter winner values into zeroed x ----------
__global__ void k_scatter(const int* __restrict__ wg, const float* __restrict__ wxr,
                          const float* __restrict__ wxi, float* __restrict__ out) {
  const int b = blockIdx.x * 256 + threadIdx.x;
  if (b < B_DIM) {
    const int g = wg[b];
    out[(size_t)b * G_DIM + g] = wxr[b];
    out[(size_t)B_DIM * G_DIM + (size_t)b * G_DIM + g] = wxi[b];
  }
}

extern "C" void kernel_launch(void* const* d_in, const int* in_sizes, int n_in,
                              void* d_out, int out_size, void* d_ws, size_t ws_size,
                              hipStream_t stream) {
  const float* H = (const float*)d_in[0];
  const float* theta = (const float*)d_in[1];
  const float* alpha = (const float*)d_in[2];
  float* out = (float*)d_out;
  char* ws = (char*)d_ws;

  ushort_t* brT = (ushort_t*)(ws + WS_BRT);
  ushort_t* biT = (ushort_t*)(ws + WS_BIT);
  ushort_t* hbf = (ushort_t*)(ws + WS_HBF);
  unsigned* rowmax = (unsigned*)(ws + WS_ROWMAX);
  int* ccnt = (int*)(ws + WS_CCNT);
  int* cg = (int*)(ws + WS_CG);
  int* wg = (int*)(ws + WS_WG);
  float* wxr = (float*)(ws + WS_WXR);
  float* wxi = (float*)(ws + WS_WXI);

  // d_out x-region doubles as scratch until the final memset+scatter:
  float* prT = out;                 // [G][N] f32, 16 MB
  float* piT = out + 4194304;       // 16 MB
  float* xabs = out + 8388608;      // [B][G] f32, 32 MB

  hipMemsetAsync(ws + WS_ROWMAX, 0, 16384, stream);  // rowmax + ccnt

  k_psi<<<dim3(G_DIM / 32, N_DIM / 32), dim3(32, 8), 0, stream>>>(theta, alpha, prT, piT, brT, biT);
  k_hconv<<<4096, 256, 0, stream>>>(H, hbf);
  k_gemm<<<256, 512, 0, stream>>>(hbf, brT, biT, xabs, rowmax);
  k_scan<<<8192, 256, 0, stream>>>(xabs, rowmax, ccnt, cg);
  k_refine<<<B_DIM, 256, 0, stream>>>(H, prT, piT, ccnt, cg, wg, wxr, wxi);
  k_y<<<B_DIM, 256, 0, stream>>>(prT, piT, wg, wxr, wxi, out);
  hipMemsetAsync(out, 0, (size_t)2 * B_DIM * G_DIM * 4, stream);  // zero x-region
  k_scatter<<<8, 256, 0, stream>>>(wg, wxr, wxi, out);
}